// Round 26
// baseline (240.030 us; speedup 1.0000x reference)
//
#include <hip/hip_runtime.h>

typedef __bf16 bf16x8 __attribute__((ext_vector_type(8)));
typedef float f32x4 __attribute__((ext_vector_type(4)));
typedef unsigned short u16x8 __attribute__((ext_vector_type(8)));
typedef unsigned short u16x4 __attribute__((ext_vector_type(4)));

__device__ __forceinline__ unsigned short f2bf(float f) {
  return __builtin_bit_cast(unsigned short, (__bf16)f);   // v_cvt_pk_bf16_f32, RNE
}

__device__ __forceinline__ void gload16(const void* g, void* l) {
  __builtin_amdgcn_global_load_lds((const __attribute__((address_space(1))) unsigned int*)g,
                                   (__attribute__((address_space(3))) unsigned int*)l,
                                   16, 0, 0);
}

// DPP row_ror reductions over 16-lane rows (VALU pipe, no LDS traffic)
template <int N>
__device__ __forceinline__ float rormax(float x) {
  int r = __builtin_amdgcn_update_dpp(0, __builtin_bit_cast(int, x), 0x120 + N, 0xF, 0xF, true);
  return fmaxf(x, __builtin_bit_cast(float, r));
}
template <int N>
__device__ __forceinline__ float rorsum(float x) {
  int r = __builtin_amdgcn_update_dpp(0, __builtin_bit_cast(int, x), 0x120 + N, 0xF, 0xF, true);
  return x + __builtin_bit_cast(float, r);
}
__device__ __forceinline__ float red16max(float x) {
  x = rormax<8>(x); x = rormax<4>(x); x = rormax<2>(x); return rormax<1>(x);
}
__device__ __forceinline__ float red16sum(float x) {
  x = rorsum<8>(x); x = rorsum<4>(x); x = rorsum<2>(x); return rorsum<1>(x);
}

// ---------------------------------------------------------------------------
// f32 -> bf16 conversion for {x, qkv_w, proj_w}
// ---------------------------------------------------------------------------
__global__ __launch_bounds__(256)
void cvt3_f32_bf16(const float* __restrict__ s0, unsigned short* __restrict__ d0, int n0,
                   const float* __restrict__ s1, unsigned short* __restrict__ d1, int n1,
                   const float* __restrict__ s2, unsigned short* __restrict__ d2)
{
  int blk = blockIdx.x;
  const float* s; unsigned short* d;
  if (blk < n0)            { s = s0; d = d0; }
  else if (blk < n0 + n1)  { s = s1; d = d1; blk -= n0; }
  else                     { s = s2; d = d2; blk -= n0 + n1; }
  const size_t e = ((size_t)blk * 256 + threadIdx.x) * 8;
  const float4 a = *(const float4*)(s + e);
  const float4 b = *(const float4*)(s + e + 4);
  u16x8 v;
  v[0] = f2bf(a.x); v[1] = f2bf(a.y); v[2] = f2bf(a.z); v[3] = f2bf(a.w);
  v[4] = f2bf(b.x); v[5] = f2bf(b.y); v[6] = f2bf(b.z); v[7] = f2bf(b.w);
  *(u16x8*)(d + e) = v;
}

// ---------------------------------------------------------------------------
// 256x192 8-phase GEMM for gemm1 (R15 ledger; best-wall config) + fused
// LDS-staged V-transpose epilogue (R17). Grid 512 = 2 exact rounds.
// ---------------------------------------------------------------------------
#define SA(buf, half, kt)                                                       \
  { gload16(Ag + (size_t)((half)*128 + srow8) * K + (kt)*64 + scol,             \
            As + (buf)*32768 + (half)*16384 + wid*1024);                        \
    gload16(Ag + (size_t)((half)*128 + 64 + srow8) * K + (kt)*64 + scol,        \
            As + (buf)*32768 + (half)*16384 + 8192 + wid*1024); }

#define SB(buf, u, kt)                                                          \
  { gload16(Bg + (size_t)((u)*64 + srow8) * K + (kt)*64 + scol,                 \
            Bs + (buf)*24576 + (u)*8192 + wid*1024); }

#define LA(buf, ih)                                                             \
  { _Pragma("unroll") for (int i = 0; i < 4; ++i) {                             \
      const int ro = (buf)*32768 + arow + ((ih)*64 + i*16)*128;                 \
      af[i][0] = *(const bf16x8*)(As + ro + cbs0);                              \
      af[i][1] = *(const bf16x8*)(As + ro + cbs1); } }

#define LB2(buf)                                                                \
  { _Pragma("unroll") for (int j = 0; j < 2; ++j) {                             \
      const int ro = (buf)*24576 + brow + j*2048;                               \
      B2[j][0] = *(const bf16x8*)(Bs + ro + cbs0);                              \
      B2[j][1] = *(const bf16x8*)(Bs + ro + cbs1); } }

#define LB1(buf)                                                                \
  { const int ro = (buf)*24576 + brow + 4096;                                   \
    B1[0] = *(const bf16x8*)(Bs + ro + cbs0);                                   \
    B1[1] = *(const bf16x8*)(Bs + ro + cbs1); }

#define M2(ih)                                                                  \
  { _Pragma("unroll") for (int i = 0; i < 4; ++i)                               \
    _Pragma("unroll") for (int j = 0; j < 2; ++j)                               \
    _Pragma("unroll") for (int kk = 0; kk < 2; ++kk)                            \
      acc[(ih)*4+i][j] = __builtin_amdgcn_mfma_f32_16x16x32_bf16(               \
          af[i][kk], B2[j][kk], acc[(ih)*4+i][j], 0, 0, 0); }

#define M1(ih)                                                                  \
  { _Pragma("unroll") for (int i = 0; i < 4; ++i)                               \
    _Pragma("unroll") for (int kk = 0; kk < 2; ++kk)                            \
      acc[(ih)*4+i][2] = __builtin_amdgcn_mfma_f32_16x16x32_bf16(               \
          af[i][kk], B1[kk], acc[(ih)*4+i][2], 0, 0, 0); }

#define BAR1_12() { asm volatile("s_waitcnt lgkmcnt(8)" ::: "memory");          \
                    __builtin_amdgcn_s_barrier();                               \
                    asm volatile("s_waitcnt lgkmcnt(0)" ::: "memory");          \
                    __builtin_amdgcn_sched_barrier(0);                          \
                    __builtin_amdgcn_s_setprio(1); }
#define BAR1()    { __builtin_amdgcn_s_barrier();                               \
                    asm volatile("s_waitcnt lgkmcnt(0)" ::: "memory");          \
                    __builtin_amdgcn_sched_barrier(0);                          \
                    __builtin_amdgcn_s_setprio(1); }
#define BAR2()    { __builtin_amdgcn_s_setprio(0); __builtin_amdgcn_s_barrier(); }
#define BAR2V3()  { __builtin_amdgcn_s_setprio(0);                              \
                    asm volatile("s_waitcnt vmcnt(3)" ::: "memory");            \
                    __builtin_amdgcn_s_barrier(); }

__global__ __launch_bounds__(512, 1)
void gemm_n192(const unsigned short* __restrict__ Ap, const unsigned short* __restrict__ Bp,
               unsigned short* __restrict__ QKout, unsigned short* __restrict__ vT,
               int M, int N, int K)
{
  extern __shared__ __align__(16) char smem[];
  char* const As = smem;            // [2][256 rows][64 k] bf16, 64KB
  char* const Bs = smem + 65536;    // [2][192 rows][64 k] bf16, 48KB
  const int tid = threadIdx.x;
  const int wid = tid >> 6, lane = tid & 63;
  const int wm = wid >> 2, wn = wid & 3;
  const int lg = lane >> 4, lr = lane & 15;

  const int gx = gridDim.x;                      // 32 N-tiles
  const int nwg = gx * (int)gridDim.y;
  int bid = (int)blockIdx.y * gx + (int)blockIdx.x;
  bid = (bid & 7) * (nwg >> 3) + (bid >> 3);     // bijective: nwg % 8 == 0
  const int m0 = (bid / gx) * 256, n0 = (bid % gx) * 192;

  const int srow8 = wid * 8 + (lane >> 3);
  const int scol  = (((lane & 7) ^ (lane >> 3)) << 3);
  const unsigned short* const Ag = Ap + (size_t)m0 * K;
  const unsigned short* const Bg = Bp + (size_t)n0 * K;

  const int cbs0 = (lg * 16) ^ ((lr & 7) << 4);
  const int cbs1 = (64 + lg * 16) ^ ((lr & 7) << 4);
  const int arow = (wm * 128 + lr) * 128;
  const int brow = (wn * 48 + lr) * 128;

  const f32x4 z4 = {0.f, 0.f, 0.f, 0.f};
  f32x4 acc[8][3];
#pragma unroll
  for (int i = 0; i < 8; ++i)
#pragma unroll
    for (int j = 0; j < 3; ++j) acc[i][j] = z4;

  const int NKT = K >> 6;
  bf16x8 af[4][2], B2[2][2], B1[2];

  SA(0, 0, 0); SA(0, 1, 0);
  SB(0, 0, 0); SB(0, 1, 0); SB(0, 2, 0);
  SB(1, 0, 1); SB(1, 1, 1); SB(1, 2, 1);
  asm volatile("s_waitcnt vmcnt(3)" ::: "memory");
  __builtin_amdgcn_s_barrier();

  for (int it = 0; it < (NKT >> 1); ++it) {
    const int t1  = 2 * it + 1;
    const int t0n = (2 * it + 2 < NKT) ? 2 * it + 2 : NKT - 1;
    const int t1n = (t1 + 2 < NKT) ? t1 + 2 : NKT - 1;

    LA(0, 0); LB2(0); SA(1, 0, t1);
    BAR1_12(); M2(0); BAR2();
    LB1(0); SA(1, 1, t1);
    BAR1(); M1(0); BAR2();
    LA(0, 1); SB(0, 0, t0n); SB(0, 1, t0n);
    BAR1(); M2(1); BAR2();
    SB(0, 2, t0n);
    BAR1(); M1(1); BAR2V3();
    LA(1, 0); LB2(1); SA(0, 0, t0n);
    BAR1_12(); M2(0); BAR2();
    LB1(1); SA(0, 1, t0n);
    BAR1(); M1(0); BAR2();
    LA(1, 1); SB(1, 0, t1n); SB(1, 1, t1n);
    BAR1(); M2(1); BAR2();
    SB(1, 2, t1n);
    BAR1(); M1(1); BAR2V3();
  }
  asm volatile("s_waitcnt vmcnt(0)" ::: "memory");

  // ---- epilogue ----
  const int d4 = 4096 - n0;
  const int vlo = d4 <= 0 ? 0 : (d4 >= 192 ? 192 : d4);

#pragma unroll
  for (int i = 0; i < 8; ++i)
#pragma unroll
    for (int j = 0; j < 3; ++j) {
      const int clb = wn * 48 + j * 16;
      if (clb < vlo) {
        const int row0 = m0 + wm * 128 + i * 16 + lg * 4;
#pragma unroll
        for (int r = 0; r < 4; ++r)
          QKout[(size_t)(row0 + r) * 4096 + n0 + clb + lr] = f2bf(acc[i][j][r]);
      }
    }

  if (vlo < 192) {
    char* const Lt = smem;                      // [ncl][256 t] bf16, <=96KB
    __syncthreads();
#pragma unroll
    for (int i = 0; i < 8; ++i)
#pragma unroll
      for (int j = 0; j < 3; ++j) {
        const int clb = wn * 48 + j * 16;
        if (clb >= vlo) {
          const int cl = clb + lr - vlo;
          const int t  = wm * 128 + i * 16 + lg * 4;
          u16x4 pack;
          pack[0] = f2bf(acc[i][j][0]); pack[1] = f2bf(acc[i][j][1]);
          pack[2] = f2bf(acc[i][j][2]); pack[3] = f2bf(acc[i][j][3]);
          *(u16x4*)(Lt + cl * 512 + ((t * 2) ^ ((cl & 7) << 4))) = pack;
        }
      }
    __syncthreads();
    const int ncl = 192 - vlo;
    const int cbase = n0 + vlo - 4096;
    const int bb = m0 >> 11, t0g = m0 & 2047;
    for (int chunk = tid; chunk < ncl * 32; chunk += 512) {
      const int cl = chunk >> 5, tt = (chunk & 31) * 8;
      u16x8 v = *(const u16x8*)(Lt + cl * 512 + ((tt * 2) ^ ((cl & 7) << 4)));
      const int gc = cbase + cl;
      *(u16x8*)(vT + ((size_t)(bb * 16 + (gc >> 7)) * 128 + (gc & 127)) * 2048 + t0g + tt) = v;
    }
  }
}

// ---------------------------------------------------------------------------
// 128x256 8-phase GEMM — gemm3 (R18, proven): 256 blocks = exactly 1 round.
// ---------------------------------------------------------------------------
#define STGA3(buf, kt)                                                          \
  { gload16(Ag + (size_t)(srow8) * K + (kt)*64 + scol,                          \
            As + (buf)*16384 + wid*1024);                                       \
    gload16(Ag + (size_t)(64 + srow8) * K + (kt)*64 + scol,                     \
            As + (buf)*16384 + 8192 + wid*1024); }

#define STGB3(buf, half, kt)                                                    \
  { gload16(Bg + (size_t)((half)*128 + srow8) * K + (kt)*64 + scol,             \
            Bs + (buf)*32768 + (half)*16384 + wid*1024);                        \
    gload16(Bg + (size_t)((half)*128 + 64 + srow8) * K + (kt)*64 + scol,        \
            Bs + (buf)*32768 + (half)*16384 + 8192 + wid*1024); }

#define LDA3(buf, ih)                                                           \
  { _Pragma("unroll") for (int i2 = 0; i2 < 2; ++i2) {                          \
      const int ro = (buf)*16384 + arow + ((ih)*32 + i2*16)*128;                \
      af[i2][0] = *(const bf16x8*)(As + ro + cbs0);                             \
      af[i2][1] = *(const bf16x8*)(As + ro + cbs1); } }

#define LDB3(buf, jh, BF)                                                       \
  { _Pragma("unroll") for (int j = 0; j < 2; ++j) {                             \
      const int ro = (buf)*32768 + brow + (((jh)*2 + j)*16)*128;                \
      BF[j][0] = *(const bf16x8*)(Bs + ro + cbs0);                              \
      BF[j][1] = *(const bf16x8*)(Bs + ro + cbs1); } }

#define MM3(ih, jh, BF)                                                         \
  { _Pragma("unroll") for (int i2 = 0; i2 < 2; ++i2)                            \
    _Pragma("unroll") for (int j = 0; j < 2; ++j)                               \
    _Pragma("unroll") for (int kk = 0; kk < 2; ++kk)                            \
      acc[(ih)*2+i2][(jh)*2+j] = __builtin_amdgcn_mfma_f32_16x16x32_bf16(       \
          af[i2][kk], BF[j][kk], acc[(ih)*2+i2][(jh)*2+j], 0, 0, 0); }

#define BAR2V4()  { __builtin_amdgcn_s_setprio(0);                              \
                    asm volatile("s_waitcnt vmcnt(4)" ::: "memory");            \
                    __builtin_amdgcn_s_barrier(); }

__global__ __launch_bounds__(512, 1)
void gemm128x256(const unsigned short* __restrict__ Ap, const unsigned short* __restrict__ Bp,
                 float* __restrict__ Outp, int M, int N, int K)
{
  extern __shared__ __align__(16) char smem[];
  char* const As = smem;            // [2][128 rows][64 k] bf16, 32KB
  char* const Bs = smem + 32768;    // [2][256 rows][64 k] bf16, 64KB
  const int tid = threadIdx.x;
  const int wid = tid >> 6, lane = tid & 63;
  const int wm = wid >> 2, wn = wid & 3;
  const int lg = lane >> 4, lr = lane & 15;

  const int gx = gridDim.x;                      // N tiles (8)
  const int nwg = gx * (int)gridDim.y;
  int bid = (int)blockIdx.y * gx + (int)blockIdx.x;
  bid = (bid & 7) * (nwg >> 3) + (bid >> 3);     // bijective: nwg % 8 == 0
  const int m0 = (bid / gx) * 128, n0 = (bid % gx) * 256;

  const int srow8 = wid * 8 + (lane >> 3);
  const int scol  = (((lane & 7) ^ (lane >> 3)) << 3);
  const unsigned short* const Ag = Ap + (size_t)m0 * K;
  const unsigned short* const Bg = Bp + (size_t)n0 * K;

  const int cbs0 = (lg * 16) ^ ((lr & 7) << 4);
  const int cbs1 = (64 + lg * 16) ^ ((lr & 7) << 4);
  const int arow = (wm * 64 + lr) * 128;
  const int brow = (wn * 64 + lr) * 128;

  const f32x4 z4 = {0.f, 0.f, 0.f, 0.f};
  f32x4 acc[4][4];
#pragma unroll
  for (int i = 0; i < 4; ++i)
#pragma unroll
    for (int j = 0; j < 4; ++j) acc[i][j] = z4;

  const int NKT = K >> 6;
  bf16x8 af[2][2], bf01[2][2], bf23[2][2];

  STGA3(0, 0); STGB3(0, 0, 0); STGB3(0, 1, 0);
  STGB3(1, 0, 1); STGB3(1, 1, 1);
  asm volatile("s_waitcnt vmcnt(4)" ::: "memory");
  __builtin_amdgcn_s_barrier();

  for (int it = 0; it < (NKT >> 1); ++it) {
    const int t1  = 2 * it + 1;
    const int t0n = (2 * it + 2 < NKT) ? 2 * it + 2 : NKT - 1;
    const int t1n = (t1 + 2 < NKT) ? t1 + 2 : NKT - 1;

    LDA3(0, 0); LDB3(0, 0, bf01); STGA3(1, t1);
    BAR1(); MM3(0, 0, bf01); BAR2();
    LDB3(0, 1, bf23);
    BAR1(); MM3(0, 1, bf23); BAR2();
    LDA3(0, 1); STGB3(0, 0, t0n);
    BAR1(); MM3(1, 0, bf01); BAR2();
    STGB3(0, 1, t0n);
    BAR1(); MM3(1, 1, bf23); BAR2V4();
    LDA3(1, 0); LDB3(1, 0, bf01); STGA3(0, t0n);
    BAR1(); MM3(0, 0, bf01); BAR2();
    LDB3(1, 1, bf23);
    BAR1(); MM3(0, 1, bf23); BAR2();
    LDA3(1, 1); STGB3(1, 0, t1n);
    BAR1(); MM3(1, 0, bf01); BAR2();
    STGB3(1, 1, t1n);
    BAR1(); MM3(1, 1, bf23); BAR2V4();
  }
  asm volatile("s_waitcnt vmcnt(0)" ::: "memory");

#pragma unroll
  for (int i = 0; i < 4; ++i)
#pragma unroll
    for (int j = 0; j < 4; ++j)
#pragma unroll
      for (int r = 0; r < 4; ++r) {
        const int row = m0 + wm * 64 + i * 16 + lg * 4 + r;
        const int col = n0 + wn * 64 + j * 16 + lr;
        Outp[(size_t)row * N + col] = acc[i][j][r];
      }
}

// ---------------------------------------------------------------------------
// Flash attention v8 + T5 setprio (best config); QK stride 4096, V from vT.
// ---------------------------------------------------------------------------
__global__ __launch_bounds__(256, 2)
void attn_fwd(const unsigned short* __restrict__ qk, const unsigned short* __restrict__ vT,
              unsigned short* __restrict__ outp)
{
  constexpr int T = 2048, ROWS = 4096;
  const int blk = blockIdx.x;
  const int qt = 31 - (blk >> 5);       // heavy tiles first (greedy LPT)
  const int bh = blk & 31;
  const int b = bh >> 4, h = bh & 15;
  const int q0 = qt * 64;
  const int tid = threadIdx.x;
  const int wid = tid >> 6, lane = tid & 63;
  const int lg = lane >> 4, lr = lane & 15;

  __shared__ __align__(16) char Ks[128 * 256];  // 32KB [128 k][128 d] swizzled
  __shared__ __align__(16) char Vt[128 * 256];  // 32KB [128 d][128 k] swizzled
  __shared__ __align__(16) char Ps[64 * 256];   // 16KB [64 q][128 k] swizzled

  const int srow = wid * 4 + (lane >> 4);
  const int scol = (((lane & 15) ^ (srow & 7)) << 3);

  const size_t qrow = (size_t)(b * T + q0 + wid * 16 + lr) * ROWS + h * 128;
  bf16x8 qf[4];
#pragma unroll
  for (int kd = 0; kd < 4; ++kd)
    qf[kd] = __builtin_bit_cast(bf16x8, *(const u16x8*)(qk + qrow + kd * 32 + lg * 8));

  const f32x4 z4 = {0.f, 0.f, 0.f, 0.f};
  f32x4 oacc[8];
#pragma unroll
  for (int jj = 0; jj < 8; ++jj) oacc[jj] = z4;
  float mrow[4] = {-1e30f, -1e30f, -1e30f, -1e30f};
  float lsum[4] = {0.f, 0.f, 0.f, 0.f};
  const float scale2 = 0.12751745f;   // (1/sqrt(128)) * log2(e)

  const int nt = (qt >> 1) + 1;
  for (int kt = 0; kt < nt; ++kt) {
    __syncthreads();
#pragma unroll
    for (int c = 0; c < 8; ++c) {
      gload16(qk + (size_t)(b * T + kt * 128 + c * 16 + srow) * ROWS + 2048 + h * 128 + scol,
              Ks + c * 4096 + wid * 1024);
      gload16(vT + ((size_t)bh * 128 + c * 16 + srow) * 2048 + kt * 128 + scol,
              Vt + c * 4096 + wid * 1024);
    }
    asm volatile("s_waitcnt vmcnt(0)" ::: "memory");
    __syncthreads();

    f32x4 sf[8];
#pragma unroll
    for (int j = 0; j < 8; ++j) sf[j] = z4;
    __builtin_amdgcn_s_setprio(1);
#pragma unroll
    for (int kd = 0; kd < 4; ++kd) {
      const int cb = (kd * 32 + lg * 8) * 2;
#pragma unroll
      for (int j = 0; j < 8; ++j) {
        const int row = j * 16 + lr;
        bf16x8 kf = *(const bf16x8*)(Ks + row * 256 + (cb ^ ((row & 7) << 4)));
        sf[j] = __builtin_amdgcn_mfma_f32_16x16x32_bf16(qf[kd], kf, sf[j], 0, 0, 0);
      }
    }
    __builtin_amdgcn_s_setprio(0);

    const bool diag = (kt == nt - 1);
#pragma unroll
    for (int j = 0; j < 8; ++j)
#pragma unroll
      for (int r = 0; r < 4; ++r) {
        float s = sf[j][r] * scale2;
        const int key = kt * 128 + j * 16 + lr;
        const int qi  = q0 + wid * 16 + lg * 4 + r;
        if (diag && key > qi) s = -1e30f;
        sf[j][r] = s;
      }
    float pm[4];
#pragma unroll
    for (int r = 0; r < 4; ++r) {
      float m0 = fmaxf(fmaxf(sf[0][r], sf[1][r]), fmaxf(sf[2][r], sf[3][r]));
      float m1 = fmaxf(fmaxf(sf[4][r], sf[5][r]), fmaxf(sf[6][r], sf[7][r]));
      pm[r] = red16max(fmaxf(m0, m1));
    }
    const float growth = fmaxf(fmaxf(pm[0] - mrow[0], pm[1] - mrow[1]),
                               fmaxf(pm[2] - mrow[2], pm[3] - mrow[3]));
    const bool resc = !__all(growth <= 11.5f);
    float alpha[4];
    if (resc) {
#pragma unroll
      for (int r = 0; r < 4; ++r) {
        const float mn = fmaxf(mrow[r], pm[r]);
        alpha[r] = exp2f(mrow[r] - mn);
        mrow[r] = mn;
      }
    }
    float rs[4] = {0.f, 0.f, 0.f, 0.f};
#pragma unroll
    for (int j = 0; j < 8; ++j)
#pragma unroll
      for (int r = 0; r < 4; ++r) {
        const float p = exp2f(sf[j][r] - mrow[r]);
        sf[j][r] = p;
        rs[r] += p;
      }
    if (resc) {
#pragma unroll
      for (int r = 0; r < 4; ++r) lsum[r] = lsum[r] * alpha[r] + red16sum(rs[r]);
    } else {
#pragma unroll
      for (int r = 0; r < 4; ++r) lsum[r] += red16sum(rs[r]);
    }

#pragma unroll
    for (int j = 0; j < 8; ++j)
#pragma unroll
      for (int r = 0; r < 4; ++r) {
        const int prow = wid * 16 + lg * 4 + r;
        const int pcol = j * 16 + lr;
        *(unsigned short*)(Ps + prow * 256 + ((pcol * 2) ^ ((prow & 7) << 4))) = f2bf(sf[j][r]);
      }
    if (resc) {
#pragma unroll
      for (int jj = 0; jj < 8; ++jj)
#pragma unroll
        for (int r = 0; r < 4; ++r) oacc[jj][r] *= alpha[r];
    }
    asm volatile("s_waitcnt lgkmcnt(0)" ::: "memory");
    __builtin_amdgcn_sched_barrier(0);

    __builtin_amdgcn_s_setprio(1);
#pragma unroll
    for (int kk = 0; kk < 4; ++kk) {
      const int prow = wid * 16 + lr;
      const int pcb = (kk * 32 + lg * 8) * 2;
      bf16x8 pf = *(const bf16x8*)(Ps + prow * 256 + (pcb ^ ((prow & 7) << 4)));
#pragma unroll
      for (int jj = 0; jj < 8; ++jj) {
        const int vrow = jj * 16 + lr;
        bf16x8 vf = *(const bf16x8*)(Vt + vrow * 256 + (pcb ^ ((vrow & 7) << 4)));
        oacc[jj] = __builtin_amdgcn_mfma_f32_16x16x32_bf16(pf, vf, oacc[jj], 0, 0, 0);
      }
    }
    __builtin_amdgcn_s_setprio(0);
  }

  // epilogue
#pragma unroll
  for (int jj = 0; jj < 8; ++jj)
#pragma unroll
    for (int r = 0; r < 4; ++r) {
      const int q = q0 + wid * 16 + lg * 4 + r;
      const int col = h * 128 + jj * 16 + lr;
      const float o = oacc[jj][r] / lsum[r];
      outp[(size_t)(b * T + q) * 2048 + col] = f2bf(o);
    }
}

// ---------------------------------------------------------------------------
extern "C" void kernel_launch(void* const* d_in, const int* in_sizes, int n_in,
                              void* d_out, int out_size, void* d_ws, size_t ws_size,
                              hipStream_t stream) {
  (void)in_sizes; (void)n_in; (void)out_size; (void)ws_size;
  const float* x     = (const float*)d_in[0];   // [2,2048,2048]
  const float* qkvw  = (const float*)d_in[1];   // [6144,2048]
  const float* projw = (const float*)d_in[2];   // [2048,2048]

  // qkv intermediate (25.2M elems) reshaped: QK row-major [4096][4096] + V^T
  unsigned short* qkb    = (unsigned short*)d_ws;               // [4096][4096]
  unsigned short* vT     = qkb + (size_t)4096 * 4096;           // [32*128][2048]
  unsigned short* attnb  = qkb + (size_t)4096 * 6144;           // [4096][2048]
  unsigned short* xb     = attnb  + (size_t)4096 * 2048;        // [4096][2048]
  unsigned short* qkvwb  = xb     + (size_t)4096 * 2048;        // [6144][2048]
  unsigned short* projwb = qkvwb  + (size_t)6144 * 2048;        // [2048][2048]
  float* out = (float*)d_out;                                   // [4096][2048] f32

  static bool attr_set = false;
  if (!attr_set) {
    hipFuncSetAttribute((const void*)gemm_n192,
                        hipFuncAttributeMaxDynamicSharedMemorySize, 114688);
    hipFuncSetAttribute((const void*)gemm128x256,
                        hipFuncAttributeMaxDynamicSharedMemorySize, 98304);
    attr_set = true;
  }

  cvt3_f32_bf16<<<4096 + 6144 + 2048, 256, 0, stream>>>(
      x, xb, 4096, qkvw, qkvwb, 6144, projw, projwb);
  gemm_n192<<<dim3(6144 / 192, 4096 / 256), 512, 114688, stream>>>(
      xb, qkvwb, qkb, vT, 4096, 6144, 2048);
  attn_fwd<<<1024, 256, 0, stream>>>(qkb, vT, attnb);
  gemm128x256<<<dim3(2048 / 256, 4096 / 128), 512, 98304, stream>>>(
      attnb, projwb, out, 4096, 2048, 2048);
}

// Round 27
// 237.230 us; speedup vs baseline: 1.0118x; 1.0118x over previous
//
#include <hip/hip_runtime.h>

typedef __bf16 bf16x8 __attribute__((ext_vector_type(8)));
typedef float f32x4 __attribute__((ext_vector_type(4)));
typedef unsigned short u16x8 __attribute__((ext_vector_type(8)));
typedef unsigned short u16x4 __attribute__((ext_vector_type(4)));

__device__ __forceinline__ unsigned short f2bf(float f) {
  return __builtin_bit_cast(unsigned short, (__bf16)f);   // v_cvt_pk_bf16_f32, RNE
}

__device__ __forceinline__ void gload16(const void* g, void* l) {
  __builtin_amdgcn_global_load_lds((const __attribute__((address_space(1))) unsigned int*)g,
                                   (__attribute__((address_space(3))) unsigned int*)l,
                                   16, 0, 0);
}

// DPP row_ror reductions over 16-lane rows (VALU pipe, no LDS traffic)
template <int N>
__device__ __forceinline__ float rormax(float x) {
  int r = __builtin_amdgcn_update_dpp(0, __builtin_bit_cast(int, x), 0x120 + N, 0xF, 0xF, true);
  return fmaxf(x, __builtin_bit_cast(float, r));
}
template <int N>
__device__ __forceinline__ float rorsum(float x) {
  int r = __builtin_amdgcn_update_dpp(0, __builtin_bit_cast(int, x), 0x120 + N, 0xF, 0xF, true);
  return x + __builtin_bit_cast(float, r);
}
__device__ __forceinline__ float red16max(float x) {
  x = rormax<8>(x); x = rormax<4>(x); x = rormax<2>(x); return rormax<1>(x);
}
__device__ __forceinline__ float red16sum(float x) {
  x = rorsum<8>(x); x = rorsum<4>(x); x = rorsum<2>(x); return rorsum<1>(x);
}

// ---------------------------------------------------------------------------
// f32 -> bf16 conversion for {x, qkv_w, proj_w}
// ---------------------------------------------------------------------------
__global__ __launch_bounds__(256)
void cvt3_f32_bf16(const float* __restrict__ s0, unsigned short* __restrict__ d0, int n0,
                   const float* __restrict__ s1, unsigned short* __restrict__ d1, int n1,
                   const float* __restrict__ s2, unsigned short* __restrict__ d2)
{
  int blk = blockIdx.x;
  const float* s; unsigned short* d;
  if (blk < n0)            { s = s0; d = d0; }
  else if (blk < n0 + n1)  { s = s1; d = d1; blk -= n0; }
  else                     { s = s2; d = d2; blk -= n0 + n1; }
  const size_t e = ((size_t)blk * 256 + threadIdx.x) * 8;
  const float4 a = *(const float4*)(s + e);
  const float4 b = *(const float4*)(s + e + 4);
  u16x8 v;
  v[0] = f2bf(a.x); v[1] = f2bf(a.y); v[2] = f2bf(a.z); v[3] = f2bf(a.w);
  v[4] = f2bf(b.x); v[5] = f2bf(b.y); v[6] = f2bf(b.z); v[7] = f2bf(b.w);
  *(u16x8*)(d + e) = v;
}

// ---------------------------------------------------------------------------
// 256x192 8-phase GEMM for gemm1 (R15 ledger; best-wall config) + fused
// LDS-staged V-transpose epilogue (R17). Grid 512 = 2 exact rounds.
// ---------------------------------------------------------------------------
#define SA(buf, half, kt)                                                       \
  { gload16(Ag + (size_t)((half)*128 + srow8) * K + (kt)*64 + scol,             \
            As + (buf)*32768 + (half)*16384 + wid*1024);                        \
    gload16(Ag + (size_t)((half)*128 + 64 + srow8) * K + (kt)*64 + scol,        \
            As + (buf)*32768 + (half)*16384 + 8192 + wid*1024); }

#define SB(buf, u, kt)                                                          \
  { gload16(Bg + (size_t)((u)*64 + srow8) * K + (kt)*64 + scol,                 \
            Bs + (buf)*24576 + (u)*8192 + wid*1024); }

#define LA(buf, ih)                                                             \
  { _Pragma("unroll") for (int i = 0; i < 4; ++i) {                             \
      const int ro = (buf)*32768 + arow + ((ih)*64 + i*16)*128;                 \
      af[i][0] = *(const bf16x8*)(As + ro + cbs0);                              \
      af[i][1] = *(const bf16x8*)(As + ro + cbs1); } }

#define LB2(buf)                                                                \
  { _Pragma("unroll") for (int j = 0; j < 2; ++j) {                             \
      const int ro = (buf)*24576 + brow + j*2048;                               \
      B2[j][0] = *(const bf16x8*)(Bs + ro + cbs0);                              \
      B2[j][1] = *(const bf16x8*)(Bs + ro + cbs1); } }

#define LB1(buf)                                                                \
  { const int ro = (buf)*24576 + brow + 4096;                                   \
    B1[0] = *(const bf16x8*)(Bs + ro + cbs0);                                   \
    B1[1] = *(const bf16x8*)(Bs + ro + cbs1); }

#define M2(ih)                                                                  \
  { _Pragma("unroll") for (int i = 0; i < 4; ++i)                               \
    _Pragma("unroll") for (int j = 0; j < 2; ++j)                               \
    _Pragma("unroll") for (int kk = 0; kk < 2; ++kk)                            \
      acc[(ih)*4+i][j] = __builtin_amdgcn_mfma_f32_16x16x32_bf16(               \
          af[i][kk], B2[j][kk], acc[(ih)*4+i][j], 0, 0, 0); }

#define M1(ih)                                                                  \
  { _Pragma("unroll") for (int i = 0; i < 4; ++i)                               \
    _Pragma("unroll") for (int kk = 0; kk < 2; ++kk)                            \
      acc[(ih)*4+i][2] = __builtin_amdgcn_mfma_f32_16x16x32_bf16(               \
          af[i][kk], B1[kk], acc[(ih)*4+i][2], 0, 0, 0); }

#define BAR1_12() { asm volatile("s_waitcnt lgkmcnt(8)" ::: "memory");          \
                    __builtin_amdgcn_s_barrier();                               \
                    asm volatile("s_waitcnt lgkmcnt(0)" ::: "memory");          \
                    __builtin_amdgcn_sched_barrier(0);                          \
                    __builtin_amdgcn_s_setprio(1); }
#define BAR1()    { __builtin_amdgcn_s_barrier();                               \
                    asm volatile("s_waitcnt lgkmcnt(0)" ::: "memory");          \
                    __builtin_amdgcn_sched_barrier(0);                          \
                    __builtin_amdgcn_s_setprio(1); }
#define BAR2()    { __builtin_amdgcn_s_setprio(0); __builtin_amdgcn_s_barrier(); }
#define BAR2V3()  { __builtin_amdgcn_s_setprio(0);                              \
                    asm volatile("s_waitcnt vmcnt(3)" ::: "memory");            \
                    __builtin_amdgcn_s_barrier(); }

__global__ __launch_bounds__(512, 1)
void gemm_n192(const unsigned short* __restrict__ Ap, const unsigned short* __restrict__ Bp,
               unsigned short* __restrict__ QKout, unsigned short* __restrict__ vT,
               int M, int N, int K)
{
  extern __shared__ __align__(16) char smem[];
  char* const As = smem;            // [2][256 rows][64 k] bf16, 64KB
  char* const Bs = smem + 65536;    // [2][192 rows][64 k] bf16, 48KB
  const int tid = threadIdx.x;
  const int wid = tid >> 6, lane = tid & 63;
  const int wm = wid >> 2, wn = wid & 3;
  const int lg = lane >> 4, lr = lane & 15;

  const int gx = gridDim.x;                      // 32 N-tiles
  const int nwg = gx * (int)gridDim.y;
  int bid = (int)blockIdx.y * gx + (int)blockIdx.x;
  bid = (bid & 7) * (nwg >> 3) + (bid >> 3);     // bijective: nwg % 8 == 0
  const int m0 = (bid / gx) * 256, n0 = (bid % gx) * 192;

  const int srow8 = wid * 8 + (lane >> 3);
  const int scol  = (((lane & 7) ^ (lane >> 3)) << 3);
  const unsigned short* const Ag = Ap + (size_t)m0 * K;
  const unsigned short* const Bg = Bp + (size_t)n0 * K;

  const int cbs0 = (lg * 16) ^ ((lr & 7) << 4);
  const int cbs1 = (64 + lg * 16) ^ ((lr & 7) << 4);
  const int arow = (wm * 128 + lr) * 128;
  const int brow = (wn * 48 + lr) * 128;

  const f32x4 z4 = {0.f, 0.f, 0.f, 0.f};
  f32x4 acc[8][3];
#pragma unroll
  for (int i = 0; i < 8; ++i)
#pragma unroll
    for (int j = 0; j < 3; ++j) acc[i][j] = z4;

  const int NKT = K >> 6;
  bf16x8 af[4][2], B2[2][2], B1[2];

  SA(0, 0, 0); SA(0, 1, 0);
  SB(0, 0, 0); SB(0, 1, 0); SB(0, 2, 0);
  SB(1, 0, 1); SB(1, 1, 1); SB(1, 2, 1);
  asm volatile("s_waitcnt vmcnt(3)" ::: "memory");
  __builtin_amdgcn_s_barrier();

  for (int it = 0; it < (NKT >> 1); ++it) {
    const int t1  = 2 * it + 1;
    const int t0n = (2 * it + 2 < NKT) ? 2 * it + 2 : NKT - 1;
    const int t1n = (t1 + 2 < NKT) ? t1 + 2 : NKT - 1;

    LA(0, 0); LB2(0); SA(1, 0, t1);
    BAR1_12(); M2(0); BAR2();
    LB1(0); SA(1, 1, t1);
    BAR1(); M1(0); BAR2();
    LA(0, 1); SB(0, 0, t0n); SB(0, 1, t0n);
    BAR1(); M2(1); BAR2();
    SB(0, 2, t0n);
    BAR1(); M1(1); BAR2V3();
    LA(1, 0); LB2(1); SA(0, 0, t0n);
    BAR1_12(); M2(0); BAR2();
    LB1(1); SA(0, 1, t0n);
    BAR1(); M1(0); BAR2();
    LA(1, 1); SB(1, 0, t1n); SB(1, 1, t1n);
    BAR1(); M2(1); BAR2();
    SB(1, 2, t1n);
    BAR1(); M1(1); BAR2V3();
  }
  asm volatile("s_waitcnt vmcnt(0)" ::: "memory");

  // ---- epilogue ----
  const int d4 = 4096 - n0;
  const int vlo = d4 <= 0 ? 0 : (d4 >= 192 ? 192 : d4);

#pragma unroll
  for (int i = 0; i < 8; ++i)
#pragma unroll
    for (int j = 0; j < 3; ++j) {
      const int clb = wn * 48 + j * 16;
      if (clb < vlo) {
        const int row0 = m0 + wm * 128 + i * 16 + lg * 4;
#pragma unroll
        for (int r = 0; r < 4; ++r)
          QKout[(size_t)(row0 + r) * 4096 + n0 + clb + lr] = f2bf(acc[i][j][r]);
      }
    }

  if (vlo < 192) {
    char* const Lt = smem;                      // [ncl][256 t] bf16, <=96KB
    __syncthreads();
#pragma unroll
    for (int i = 0; i < 8; ++i)
#pragma unroll
      for (int j = 0; j < 3; ++j) {
        const int clb = wn * 48 + j * 16;
        if (clb >= vlo) {
          const int cl = clb + lr - vlo;
          const int t  = wm * 128 + i * 16 + lg * 4;
          u16x4 pack;
          pack[0] = f2bf(acc[i][j][0]); pack[1] = f2bf(acc[i][j][1]);
          pack[2] = f2bf(acc[i][j][2]); pack[3] = f2bf(acc[i][j][3]);
          *(u16x4*)(Lt + cl * 512 + ((t * 2) ^ ((cl & 7) << 4))) = pack;
        }
      }
    __syncthreads();
    const int ncl = 192 - vlo;
    const int cbase = n0 + vlo - 4096;
    const int bb = m0 >> 11, t0g = m0 & 2047;
    for (int chunk = tid; chunk < ncl * 32; chunk += 512) {
      const int cl = chunk >> 5, tt = (chunk & 31) * 8;
      u16x8 v = *(const u16x8*)(Lt + cl * 512 + ((tt * 2) ^ ((cl & 7) << 4)));
      const int gc = cbase + cl;
      *(u16x8*)(vT + ((size_t)(bb * 16 + (gc >> 7)) * 128 + (gc & 127)) * 2048 + t0g + tt) = v;
    }
  }
}

// ---------------------------------------------------------------------------
// 128x256 8-phase GEMM — gemm3 (R18, proven): 256 blocks = exactly 1 round.
// ---------------------------------------------------------------------------
#define STGA3(buf, kt)                                                          \
  { gload16(Ag + (size_t)(srow8) * K + (kt)*64 + scol,                          \
            As + (buf)*16384 + wid*1024);                                       \
    gload16(Ag + (size_t)(64 + srow8) * K + (kt)*64 + scol,                     \
            As + (buf)*16384 + 8192 + wid*1024); }

#define STGB3(buf, half, kt)                                                    \
  { gload16(Bg + (size_t)((half)*128 + srow8) * K + (kt)*64 + scol,             \
            Bs + (buf)*32768 + (half)*16384 + wid*1024);                        \
    gload16(Bg + (size_t)((half)*128 + 64 + srow8) * K + (kt)*64 + scol,        \
            Bs + (buf)*32768 + (half)*16384 + 8192 + wid*1024); }

#define LDA3(buf, ih)                                                           \
  { _Pragma("unroll") for (int i2 = 0; i2 < 2; ++i2) {                          \
      const int ro = (buf)*16384 + arow + ((ih)*32 + i2*16)*128;                \
      af[i2][0] = *(const bf16x8*)(As + ro + cbs0);                             \
      af[i2][1] = *(const bf16x8*)(As + ro + cbs1); } }

#define LDB3(buf, jh, BF)                                                       \
  { _Pragma("unroll") for (int j = 0; j < 2; ++j) {                             \
      const int ro = (buf)*32768 + brow + (((jh)*2 + j)*16)*128;                \
      BF[j][0] = *(const bf16x8*)(Bs + ro + cbs0);                              \
      BF[j][1] = *(const bf16x8*)(Bs + ro + cbs1); } }

#define MM3(ih, jh, BF)                                                         \
  { _Pragma("unroll") for (int i2 = 0; i2 < 2; ++i2)                            \
    _Pragma("unroll") for (int j = 0; j < 2; ++j)                               \
    _Pragma("unroll") for (int kk = 0; kk < 2; ++kk)                            \
      acc[(ih)*2+i2][(jh)*2+j] = __builtin_amdgcn_mfma_f32_16x16x32_bf16(       \
          af[i2][kk], BF[j][kk], acc[(ih)*2+i2][(jh)*2+j], 0, 0, 0); }

#define BAR2V4()  { __builtin_amdgcn_s_setprio(0);                              \
                    asm volatile("s_waitcnt vmcnt(4)" ::: "memory");            \
                    __builtin_amdgcn_s_barrier(); }

__global__ __launch_bounds__(512, 1)
void gemm128x256(const unsigned short* __restrict__ Ap, const unsigned short* __restrict__ Bp,
                 float* __restrict__ Outp, int M, int N, int K)
{
  extern __shared__ __align__(16) char smem[];
  char* const As = smem;            // [2][128 rows][64 k] bf16, 32KB
  char* const Bs = smem + 32768;    // [2][256 rows][64 k] bf16, 64KB
  const int tid = threadIdx.x;
  const int wid = tid >> 6, lane = tid & 63;
  const int wm = wid >> 2, wn = wid & 3;
  const int lg = lane >> 4, lr = lane & 15;

  const int gx = gridDim.x;                      // N tiles (8)
  const int nwg = gx * (int)gridDim.y;
  int bid = (int)blockIdx.y * gx + (int)blockIdx.x;
  bid = (bid & 7) * (nwg >> 3) + (bid >> 3);     // bijective: nwg % 8 == 0
  const int m0 = (bid / gx) * 128, n0 = (bid % gx) * 256;

  const int srow8 = wid * 8 + (lane >> 3);
  const int scol  = (((lane & 7) ^ (lane >> 3)) << 3);
  const unsigned short* const Ag = Ap + (size_t)m0 * K;
  const unsigned short* const Bg = Bp + (size_t)n0 * K;

  const int cbs0 = (lg * 16) ^ ((lr & 7) << 4);
  const int cbs1 = (64 + lg * 16) ^ ((lr & 7) << 4);
  const int arow = (wm * 64 + lr) * 128;
  const int brow = (wn * 64 + lr) * 128;

  const f32x4 z4 = {0.f, 0.f, 0.f, 0.f};
  f32x4 acc[4][4];
#pragma unroll
  for (int i = 0; i < 4; ++i)
#pragma unroll
    for (int j = 0; j < 4; ++j) acc[i][j] = z4;

  const int NKT = K >> 6;
  bf16x8 af[2][2], bf01[2][2], bf23[2][2];

  STGA3(0, 0); STGB3(0, 0, 0); STGB3(0, 1, 0);
  STGB3(1, 0, 1); STGB3(1, 1, 1);
  asm volatile("s_waitcnt vmcnt(4)" ::: "memory");
  __builtin_amdgcn_s_barrier();

  for (int it = 0; it < (NKT >> 1); ++it) {
    const int t1  = 2 * it + 1;
    const int t0n = (2 * it + 2 < NKT) ? 2 * it + 2 : NKT - 1;
    const int t1n = (t1 + 2 < NKT) ? t1 + 2 : NKT - 1;

    LDA3(0, 0); LDB3(0, 0, bf01); STGA3(1, t1);
    BAR1(); MM3(0, 0, bf01); BAR2();
    LDB3(0, 1, bf23);
    BAR1(); MM3(0, 1, bf23); BAR2();
    LDA3(0, 1); STGB3(0, 0, t0n);
    BAR1(); MM3(1, 0, bf01); BAR2();
    STGB3(0, 1, t0n);
    BAR1(); MM3(1, 1, bf23); BAR2V4();
    LDA3(1, 0); LDB3(1, 0, bf01); STGA3(0, t0n);
    BAR1(); MM3(0, 0, bf01); BAR2();
    LDB3(1, 1, bf23);
    BAR1(); MM3(0, 1, bf23); BAR2();
    LDA3(1, 1); STGB3(1, 0, t1n);
    BAR1(); MM3(1, 0, bf01); BAR2();
    STGB3(1, 1, t1n);
    BAR1(); MM3(1, 1, bf23); BAR2V4();
  }
  asm volatile("s_waitcnt vmcnt(0)" ::: "memory");

#pragma unroll
  for (int i = 0; i < 4; ++i)
#pragma unroll
    for (int j = 0; j < 4; ++j)
#pragma unroll
      for (int r = 0; r < 4; ++r) {
        const int row = m0 + wm * 64 + i * 16 + lg * 4 + r;
        const int col = n0 + wn * 64 + j * 16 + lr;
        Outp[(size_t)row * N + col] = acc[i][j][r];
      }
}

// ---------------------------------------------------------------------------
// Flash attention v8 + T5 setprio (best config); QK stride 4096, V from vT.
// ---------------------------------------------------------------------------
__global__ __launch_bounds__(256, 2)
void attn_fwd(const unsigned short* __restrict__ qk, const unsigned short* __restrict__ vT,
              unsigned short* __restrict__ outp)
{
  constexpr int T = 2048, ROWS = 4096;
  const int blk = blockIdx.x;
  const int qt = 31 - (blk >> 5);       // heavy tiles first (greedy LPT)
  const int bh = blk & 31;
  const int b = bh >> 4, h = bh & 15;
  const int q0 = qt * 64;
  const int tid = threadIdx.x;
  const int wid = tid >> 6, lane = tid & 63;
  const int lg = lane >> 4, lr = lane & 15;

  __shared__ __align__(16) char Ks[128 * 256];  // 32KB [128 k][128 d] swizzled
  __shared__ __align__(16) char Vt[128 * 256];  // 32KB [128 d][128 k] swizzled
  __shared__ __align__(16) char Ps[64 * 256];   // 16KB [64 q][128 k] swizzled

  const int srow = wid * 4 + (lane >> 4);
  const int scol = (((lane & 15) ^ (srow & 7)) << 3);

  const size_t qrow = (size_t)(b * T + q0 + wid * 16 + lr) * ROWS + h * 128;
  bf16x8 qf[4];
#pragma unroll
  for (int kd = 0; kd < 4; ++kd)
    qf[kd] = __builtin_bit_cast(bf16x8, *(const u16x8*)(qk + qrow + kd * 32 + lg * 8));

  const f32x4 z4 = {0.f, 0.f, 0.f, 0.f};
  f32x4 oacc[8];
#pragma unroll
  for (int jj = 0; jj < 8; ++jj) oacc[jj] = z4;
  float mrow[4] = {-1e30f, -1e30f, -1e30f, -1e30f};
  float lsum[4] = {0.f, 0.f, 0.f, 0.f};
  const float scale2 = 0.12751745f;   // (1/sqrt(128)) * log2(e)

  const int nt = (qt >> 1) + 1;
  for (int kt = 0; kt < nt; ++kt) {
    __syncthreads();
#pragma unroll
    for (int c = 0; c < 8; ++c) {
      gload16(qk + (size_t)(b * T + kt * 128 + c * 16 + srow) * ROWS + 2048 + h * 128 + scol,
              Ks + c * 4096 + wid * 1024);
      gload16(vT + ((size_t)bh * 128 + c * 16 + srow) * 2048 + kt * 128 + scol,
              Vt + c * 4096 + wid * 1024);
    }
    asm volatile("s_waitcnt vmcnt(0)" ::: "memory");
    __syncthreads();

    f32x4 sf[8];
#pragma unroll
    for (int j = 0; j < 8; ++j) sf[j] = z4;
    __builtin_amdgcn_s_setprio(1);
#pragma unroll
    for (int kd = 0; kd < 4; ++kd) {
      const int cb = (kd * 32 + lg * 8) * 2;
#pragma unroll
      for (int j = 0; j < 8; ++j) {
        const int row = j * 16 + lr;
        bf16x8 kf = *(const bf16x8*)(Ks + row * 256 + (cb ^ ((row & 7) << 4)));
        sf[j] = __builtin_amdgcn_mfma_f32_16x16x32_bf16(qf[kd], kf, sf[j], 0, 0, 0);
      }
    }
    __builtin_amdgcn_s_setprio(0);

    const bool diag = (kt == nt - 1);
#pragma unroll
    for (int j = 0; j < 8; ++j)
#pragma unroll
      for (int r = 0; r < 4; ++r) {
        float s = sf[j][r] * scale2;
        const int key = kt * 128 + j * 16 + lr;
        const int qi  = q0 + wid * 16 + lg * 4 + r;
        if (diag && key > qi) s = -1e30f;
        sf[j][r] = s;
      }
    float pm[4];
#pragma unroll
    for (int r = 0; r < 4; ++r) {
      float m0 = fmaxf(fmaxf(sf[0][r], sf[1][r]), fmaxf(sf[2][r], sf[3][r]));
      float m1 = fmaxf(fmaxf(sf[4][r], sf[5][r]), fmaxf(sf[6][r], sf[7][r]));
      pm[r] = red16max(fmaxf(m0, m1));
    }
    const float growth = fmaxf(fmaxf(pm[0] - mrow[0], pm[1] - mrow[1]),
                               fmaxf(pm[2] - mrow[2], pm[3] - mrow[3]));
    const bool resc = !__all(growth <= 11.5f);
    float alpha[4];
    if (resc) {
#pragma unroll
      for (int r = 0; r < 4; ++r) {
        const float mn = fmaxf(mrow[r], pm[r]);
        alpha[r] = exp2f(mrow[r] - mn);
        mrow[r] = mn;
      }
    }
    float rs[4] = {0.f, 0.f, 0.f, 0.f};
#pragma unroll
    for (int j = 0; j < 8; ++j)
#pragma unroll
      for (int r = 0; r < 4; ++r) {
        const float p = exp2f(sf[j][r] - mrow[r]);
        sf[j][r] = p;
        rs[r] += p;
      }
    if (resc) {
#pragma unroll
      for (int r = 0; r < 4; ++r) lsum[r] = lsum[r] * alpha[r] + red16sum(rs[r]);
    } else {
#pragma unroll
      for (int r = 0; r < 4; ++r) lsum[r] += red16sum(rs[r]);
    }

#pragma unroll
    for (int j = 0; j < 8; ++j)
#pragma unroll
      for (int r = 0; r < 4; ++r) {
        const int prow = wid * 16 + lg * 4 + r;
        const int pcol = j * 16 + lr;
        *(unsigned short*)(Ps + prow * 256 + ((pcol * 2) ^ ((prow & 7) << 4))) = f2bf(sf[j][r]);
      }
    if (resc) {
#pragma unroll
      for (int jj = 0; jj < 8; ++jj)
#pragma unroll
        for (int r = 0; r < 4; ++r) oacc[jj][r] *= alpha[r];
    }
    asm volatile("s_waitcnt lgkmcnt(0)" ::: "memory");
    __builtin_amdgcn_sched_barrier(0);

    __builtin_amdgcn_s_setprio(1);
#pragma unroll
    for (int kk = 0; kk < 4; ++kk) {
      const int prow = wid * 16 + lr;
      const int pcb = (kk * 32 + lg * 8) * 2;
      bf16x8 pf = *(const bf16x8*)(Ps + prow * 256 + (pcb ^ ((prow & 7) << 4)));
#pragma unroll
      for (int jj = 0; jj < 8; ++jj) {
        const int vrow = jj * 16 + lr;
        bf16x8 vf = *(const bf16x8*)(Vt + vrow * 256 + (pcb ^ ((vrow & 7) << 4)));
        oacc[jj] = __builtin_amdgcn_mfma_f32_16x16x32_bf16(pf, vf, oacc[jj], 0, 0, 0);
      }
    }
    __builtin_amdgcn_s_setprio(0);
  }

  // epilogue
#pragma unroll
  for (int jj = 0; jj < 8; ++jj)
#pragma unroll
    for (int r = 0; r < 4; ++r) {
      const int q = q0 + wid * 16 + lg * 4 + r;
      const int col = h * 128 + jj * 16 + lr;
      const float o = oacc[jj][r] / lsum[r];
      outp[(size_t)(b * T + q) * 2048 + col] = f2bf(o);
    }
}

// ---------------------------------------------------------------------------
extern "C" void kernel_launch(void* const* d_in, const int* in_sizes, int n_in,
                              void* d_out, int out_size, void* d_ws, size_t ws_size,
                              hipStream_t stream) {
  (void)in_sizes; (void)n_in; (void)out_size; (void)ws_size;
  const float* x     = (const float*)d_in[0];   // [2,2048,2048]
  const float* qkvw  = (const float*)d_in[1];   // [6144,2048]
  const float* projw = (const float*)d_in[2];   // [2048,2048]

  // qkv intermediate (25.2M elems) reshaped: QK row-major [4096][4096] + V^T
  unsigned short* qkb    = (unsigned short*)d_ws;               // [4096][4096]
  unsigned short* vT     = qkb + (size_t)4096 * 4096;           // [32*128][2048]
  unsigned short* attnb  = qkb + (size_t)4096 * 6144;           // [4096][2048]
  unsigned short* xb     = attnb  + (size_t)4096 * 2048;        // [4096][2048]
  unsigned short* qkvwb  = xb     + (size_t)4096 * 2048;        // [6144][2048]
  unsigned short* projwb = qkvwb  + (size_t)6144 * 2048;        // [2048][2048]
  float* out = (float*)d_out;                                   // [4096][2048] f32

  static bool attr_set = false;
  if (!attr_set) {
    hipFuncSetAttribute((const void*)gemm_n192,
                        hipFuncAttributeMaxDynamicSharedMemorySize, 114688);
    hipFuncSetAttribute((const void*)gemm128x256,
                        hipFuncAttributeMaxDynamicSharedMemorySize, 98304);
    attr_set = true;
  }

  cvt3_f32_bf16<<<4096 + 6144 + 2048, 256, 0, stream>>>(
      x, xb, 4096, qkvw, qkvwb, 6144, projw, projwb);
  gemm_n192<<<dim3(6144 / 192, 4096 / 256), 512, 114688, stream>>>(
      xb, qkvwb, qkb, vT, 4096, 6144, 2048);
  attn_fwd<<<1024, 256, 0, stream>>>(qkb, vT, attnb);
  gemm128x256<<<dim3(2048 / 256, 4096 / 128), 512, 98304, stream>>>(
      attnb, projwb, out, 4096, 2048, 2048);
}

// Round 28
// 236.038 us; speedup vs baseline: 1.0169x; 1.0051x over previous
//
#include <hip/hip_runtime.h>

typedef __bf16 bf16x8 __attribute__((ext_vector_type(8)));
typedef float f32x4 __attribute__((ext_vector_type(4)));
typedef unsigned short u16x8 __attribute__((ext_vector_type(8)));
typedef unsigned short u16x4 __attribute__((ext_vector_type(4)));

__device__ __forceinline__ unsigned short f2bf(float f) {
  return __builtin_bit_cast(unsigned short, (__bf16)f);   // v_cvt_pk_bf16_f32, RNE
}

__device__ __forceinline__ void gload16(const void* g, void* l) {
  __builtin_amdgcn_global_load_lds((const __attribute__((address_space(1))) unsigned int*)g,
                                   (__attribute__((address_space(3))) unsigned int*)l,
                                   16, 0, 0);
}

// DPP row_ror reductions over 16-lane rows (VALU pipe, no LDS traffic)
template <int N>
__device__ __forceinline__ float rormax(float x) {
  int r = __builtin_amdgcn_update_dpp(0, __builtin_bit_cast(int, x), 0x120 + N, 0xF, 0xF, true);
  return fmaxf(x, __builtin_bit_cast(float, r));
}
template <int N>
__device__ __forceinline__ float rorsum(float x) {
  int r = __builtin_amdgcn_update_dpp(0, __builtin_bit_cast(int, x), 0x120 + N, 0xF, 0xF, true);
  return x + __builtin_bit_cast(float, r);
}
__device__ __forceinline__ float red16max(float x) {
  x = rormax<8>(x); x = rormax<4>(x); x = rormax<2>(x); return rormax<1>(x);
}
__device__ __forceinline__ float red16sum(float x) {
  x = rorsum<8>(x); x = rorsum<4>(x); x = rorsum<2>(x); return rorsum<1>(x);
}

// ---------------------------------------------------------------------------
// f32 -> bf16 conversion for {x, qkv_w, proj_w}
// ---------------------------------------------------------------------------
__global__ __launch_bounds__(256)
void cvt3_f32_bf16(const float* __restrict__ s0, unsigned short* __restrict__ d0, int n0,
                   const float* __restrict__ s1, unsigned short* __restrict__ d1, int n1,
                   const float* __restrict__ s2, unsigned short* __restrict__ d2)
{
  int blk = blockIdx.x;
  const float* s; unsigned short* d;
  if (blk < n0)            { s = s0; d = d0; }
  else if (blk < n0 + n1)  { s = s1; d = d1; blk -= n0; }
  else                     { s = s2; d = d2; blk -= n0 + n1; }
  const size_t e = ((size_t)blk * 256 + threadIdx.x) * 8;
  const float4 a = *(const float4*)(s + e);
  const float4 b = *(const float4*)(s + e + 4);
  u16x8 v;
  v[0] = f2bf(a.x); v[1] = f2bf(a.y); v[2] = f2bf(a.z); v[3] = f2bf(a.w);
  v[4] = f2bf(b.x); v[5] = f2bf(b.y); v[6] = f2bf(b.z); v[7] = f2bf(b.w);
  *(u16x8*)(d + e) = v;
}

// ---------------------------------------------------------------------------
// 256x192 8-phase GEMM for gemm1 (R15 ledger; best-wall config) + fused
// LDS-staged V-transpose epilogue (R17). Grid 512 = 2 exact rounds.
// ---------------------------------------------------------------------------
#define SA(buf, half, kt)                                                       \
  { gload16(Ag + (size_t)((half)*128 + srow8) * K + (kt)*64 + scol,             \
            As + (buf)*32768 + (half)*16384 + wid*1024);                        \
    gload16(Ag + (size_t)((half)*128 + 64 + srow8) * K + (kt)*64 + scol,        \
            As + (buf)*32768 + (half)*16384 + 8192 + wid*1024); }

#define SB(buf, u, kt)                                                          \
  { gload16(Bg + (size_t)((u)*64 + srow8) * K + (kt)*64 + scol,                 \
            Bs + (buf)*24576 + (u)*8192 + wid*1024); }

#define LA(buf, ih)                                                             \
  { _Pragma("unroll") for (int i = 0; i < 4; ++i) {                             \
      const int ro = (buf)*32768 + arow + ((ih)*64 + i*16)*128;                 \
      af[i][0] = *(const bf16x8*)(As + ro + cbs0);                              \
      af[i][1] = *(const bf16x8*)(As + ro + cbs1); } }

#define LB2(buf)                                                                \
  { _Pragma("unroll") for (int j = 0; j < 2; ++j) {                             \
      const int ro = (buf)*24576 + brow + j*2048;                               \
      B2[j][0] = *(const bf16x8*)(Bs + ro + cbs0);                              \
      B2[j][1] = *(const bf16x8*)(Bs + ro + cbs1); } }

#define LB1(buf)                                                                \
  { const int ro = (buf)*24576 + brow + 4096;                                   \
    B1[0] = *(const bf16x8*)(Bs + ro + cbs0);                                   \
    B1[1] = *(const bf16x8*)(Bs + ro + cbs1); }

#define M2(ih)                                                                  \
  { _Pragma("unroll") for (int i = 0; i < 4; ++i)                               \
    _Pragma("unroll") for (int j = 0; j < 2; ++j)                               \
    _Pragma("unroll") for (int kk = 0; kk < 2; ++kk)                            \
      acc[(ih)*4+i][j] = __builtin_amdgcn_mfma_f32_16x16x32_bf16(               \
          af[i][kk], B2[j][kk], acc[(ih)*4+i][j], 0, 0, 0); }

#define M1(ih)                                                                  \
  { _Pragma("unroll") for (int i = 0; i < 4; ++i)                               \
    _Pragma("unroll") for (int kk = 0; kk < 2; ++kk)                            \
      acc[(ih)*4+i][2] = __builtin_amdgcn_mfma_f32_16x16x32_bf16(               \
          af[i][kk], B1[kk], acc[(ih)*4+i][2], 0, 0, 0); }

#define BAR1_12() { asm volatile("s_waitcnt lgkmcnt(8)" ::: "memory");          \
                    __builtin_amdgcn_s_barrier();                               \
                    asm volatile("s_waitcnt lgkmcnt(0)" ::: "memory");          \
                    __builtin_amdgcn_sched_barrier(0);                          \
                    __builtin_amdgcn_s_setprio(1); }
#define BAR1()    { __builtin_amdgcn_s_barrier();                               \
                    asm volatile("s_waitcnt lgkmcnt(0)" ::: "memory");          \
                    __builtin_amdgcn_sched_barrier(0);                          \
                    __builtin_amdgcn_s_setprio(1); }
#define BAR2()    { __builtin_amdgcn_s_setprio(0); __builtin_amdgcn_s_barrier(); }
#define BAR2V3()  { __builtin_amdgcn_s_setprio(0);                              \
                    asm volatile("s_waitcnt vmcnt(3)" ::: "memory");            \
                    __builtin_amdgcn_s_barrier(); }

__global__ __launch_bounds__(512, 1)
void gemm_n192(const unsigned short* __restrict__ Ap, const unsigned short* __restrict__ Bp,
               unsigned short* __restrict__ QKout, unsigned short* __restrict__ vT,
               int M, int N, int K)
{
  extern __shared__ __align__(16) char smem[];
  char* const As = smem;            // [2][256 rows][64 k] bf16, 64KB
  char* const Bs = smem + 65536;    // [2][192 rows][64 k] bf16, 48KB
  const int tid = threadIdx.x;
  const int wid = tid >> 6, lane = tid & 63;
  const int wm = wid >> 2, wn = wid & 3;
  const int lg = lane >> 4, lr = lane & 15;

  const int gx = gridDim.x;                      // 32 N-tiles
  const int nwg = gx * (int)gridDim.y;
  int bid = (int)blockIdx.y * gx + (int)blockIdx.x;
  bid = (bid & 7) * (nwg >> 3) + (bid >> 3);     // bijective: nwg % 8 == 0
  const int m0 = (bid / gx) * 256, n0 = (bid % gx) * 192;

  const int srow8 = wid * 8 + (lane >> 3);
  const int scol  = (((lane & 7) ^ (lane >> 3)) << 3);
  const unsigned short* const Ag = Ap + (size_t)m0 * K;
  const unsigned short* const Bg = Bp + (size_t)n0 * K;

  const int cbs0 = (lg * 16) ^ ((lr & 7) << 4);
  const int cbs1 = (64 + lg * 16) ^ ((lr & 7) << 4);
  const int arow = (wm * 128 + lr) * 128;
  const int brow = (wn * 48 + lr) * 128;

  const f32x4 z4 = {0.f, 0.f, 0.f, 0.f};
  f32x4 acc[8][3];
#pragma unroll
  for (int i = 0; i < 8; ++i)
#pragma unroll
    for (int j = 0; j < 3; ++j) acc[i][j] = z4;

  const int NKT = K >> 6;
  bf16x8 af[4][2], B2[2][2], B1[2];

  SA(0, 0, 0); SA(0, 1, 0);
  SB(0, 0, 0); SB(0, 1, 0); SB(0, 2, 0);
  SB(1, 0, 1); SB(1, 1, 1); SB(1, 2, 1);
  asm volatile("s_waitcnt vmcnt(3)" ::: "memory");
  __builtin_amdgcn_s_barrier();

  for (int it = 0; it < (NKT >> 1); ++it) {
    const int t1  = 2 * it + 1;
    const int t0n = (2 * it + 2 < NKT) ? 2 * it + 2 : NKT - 1;
    const int t1n = (t1 + 2 < NKT) ? t1 + 2 : NKT - 1;

    LA(0, 0); LB2(0); SA(1, 0, t1);
    BAR1_12(); M2(0); BAR2();
    LB1(0); SA(1, 1, t1);
    BAR1(); M1(0); BAR2();
    LA(0, 1); SB(0, 0, t0n); SB(0, 1, t0n);
    BAR1(); M2(1); BAR2();
    SB(0, 2, t0n);
    BAR1(); M1(1); BAR2V3();
    LA(1, 0); LB2(1); SA(0, 0, t0n);
    BAR1_12(); M2(0); BAR2();
    LB1(1); SA(0, 1, t0n);
    BAR1(); M1(0); BAR2();
    LA(1, 1); SB(1, 0, t1n); SB(1, 1, t1n);
    BAR1(); M2(1); BAR2();
    SB(1, 2, t1n);
    BAR1(); M1(1); BAR2V3();
  }
  asm volatile("s_waitcnt vmcnt(0)" ::: "memory");

  // ---- epilogue ----
  const int d4 = 4096 - n0;
  const int vlo = d4 <= 0 ? 0 : (d4 >= 192 ? 192 : d4);

#pragma unroll
  for (int i = 0; i < 8; ++i)
#pragma unroll
    for (int j = 0; j < 3; ++j) {
      const int clb = wn * 48 + j * 16;
      if (clb < vlo) {
        const int row0 = m0 + wm * 128 + i * 16 + lg * 4;
#pragma unroll
        for (int r = 0; r < 4; ++r)
          QKout[(size_t)(row0 + r) * 4096 + n0 + clb + lr] = f2bf(acc[i][j][r]);
      }
    }

  if (vlo < 192) {
    char* const Lt = smem;                      // [ncl][256 t] bf16, <=96KB
    __syncthreads();
#pragma unroll
    for (int i = 0; i < 8; ++i)
#pragma unroll
      for (int j = 0; j < 3; ++j) {
        const int clb = wn * 48 + j * 16;
        if (clb >= vlo) {
          const int cl = clb + lr - vlo;
          const int t  = wm * 128 + i * 16 + lg * 4;
          u16x4 pack;
          pack[0] = f2bf(acc[i][j][0]); pack[1] = f2bf(acc[i][j][1]);
          pack[2] = f2bf(acc[i][j][2]); pack[3] = f2bf(acc[i][j][3]);
          *(u16x4*)(Lt + cl * 512 + ((t * 2) ^ ((cl & 7) << 4))) = pack;
        }
      }
    __syncthreads();
    const int ncl = 192 - vlo;
    const int cbase = n0 + vlo - 4096;
    const int bb = m0 >> 11, t0g = m0 & 2047;
    for (int chunk = tid; chunk < ncl * 32; chunk += 512) {
      const int cl = chunk >> 5, tt = (chunk & 31) * 8;
      u16x8 v = *(const u16x8*)(Lt + cl * 512 + ((tt * 2) ^ ((cl & 7) << 4)));
      const int gc = cbase + cl;
      *(u16x8*)(vT + ((size_t)(bb * 16 + (gc >> 7)) * 128 + (gc & 127)) * 2048 + t0g + tt) = v;
    }
  }
}

// ---------------------------------------------------------------------------
// 128x256 8-phase GEMM — gemm3 (R18, proven): 256 blocks = exactly 1 round.
// ---------------------------------------------------------------------------
#define STGA3(buf, kt)                                                          \
  { gload16(Ag + (size_t)(srow8) * K + (kt)*64 + scol,                          \
            As + (buf)*16384 + wid*1024);                                       \
    gload16(Ag + (size_t)(64 + srow8) * K + (kt)*64 + scol,                     \
            As + (buf)*16384 + 8192 + wid*1024); }

#define STGB3(buf, half, kt)                                                    \
  { gload16(Bg + (size_t)((half)*128 + srow8) * K + (kt)*64 + scol,             \
            Bs + (buf)*32768 + (half)*16384 + wid*1024);                        \
    gload16(Bg + (size_t)((half)*128 + 64 + srow8) * K + (kt)*64 + scol,        \
            Bs + (buf)*32768 + (half)*16384 + 8192 + wid*1024); }

#define LDA3(buf, ih)                                                           \
  { _Pragma("unroll") for (int i2 = 0; i2 < 2; ++i2) {                          \
      const int ro = (buf)*16384 + arow + ((ih)*32 + i2*16)*128;                \
      af[i2][0] = *(const bf16x8*)(As + ro + cbs0);                             \
      af[i2][1] = *(const bf16x8*)(As + ro + cbs1); } }

#define LDB3(buf, jh, BF)                                                       \
  { _Pragma("unroll") for (int j = 0; j < 2; ++j) {                             \
      const int ro = (buf)*32768 + brow + (((jh)*2 + j)*16)*128;                \
      BF[j][0] = *(const bf16x8*)(Bs + ro + cbs0);                              \
      BF[j][1] = *(const bf16x8*)(Bs + ro + cbs1); } }

#define MM3(ih, jh, BF)                                                         \
  { _Pragma("unroll") for (int i2 = 0; i2 < 2; ++i2)                            \
    _Pragma("unroll") for (int j = 0; j < 2; ++j)                               \
    _Pragma("unroll") for (int kk = 0; kk < 2; ++kk)                            \
      acc[(ih)*2+i2][(jh)*2+j] = __builtin_amdgcn_mfma_f32_16x16x32_bf16(       \
          af[i2][kk], BF[j][kk], acc[(ih)*2+i2][(jh)*2+j], 0, 0, 0); }

#define BAR2V4()  { __builtin_amdgcn_s_setprio(0);                              \
                    asm volatile("s_waitcnt vmcnt(4)" ::: "memory");            \
                    __builtin_amdgcn_s_barrier(); }

__global__ __launch_bounds__(512, 1)
void gemm128x256(const unsigned short* __restrict__ Ap, const unsigned short* __restrict__ Bp,
                 float* __restrict__ Outp, int M, int N, int K)
{
  extern __shared__ __align__(16) char smem[];
  char* const As = smem;            // [2][128 rows][64 k] bf16, 32KB
  char* const Bs = smem + 32768;    // [2][256 rows][64 k] bf16, 64KB
  const int tid = threadIdx.x;
  const int wid = tid >> 6, lane = tid & 63;
  const int wm = wid >> 2, wn = wid & 3;
  const int lg = lane >> 4, lr = lane & 15;

  const int gx = gridDim.x;                      // N tiles (8)
  const int nwg = gx * (int)gridDim.y;
  int bid = (int)blockIdx.y * gx + (int)blockIdx.x;
  bid = (bid & 7) * (nwg >> 3) + (bid >> 3);     // bijective: nwg % 8 == 0
  const int m0 = (bid / gx) * 128, n0 = (bid % gx) * 256;

  const int srow8 = wid * 8 + (lane >> 3);
  const int scol  = (((lane & 7) ^ (lane >> 3)) << 3);
  const unsigned short* const Ag = Ap + (size_t)m0 * K;
  const unsigned short* const Bg = Bp + (size_t)n0 * K;

  const int cbs0 = (lg * 16) ^ ((lr & 7) << 4);
  const int cbs1 = (64 + lg * 16) ^ ((lr & 7) << 4);
  const int arow = (wm * 64 + lr) * 128;
  const int brow = (wn * 64 + lr) * 128;

  const f32x4 z4 = {0.f, 0.f, 0.f, 0.f};
  f32x4 acc[4][4];
#pragma unroll
  for (int i = 0; i < 4; ++i)
#pragma unroll
    for (int j = 0; j < 4; ++j) acc[i][j] = z4;

  const int NKT = K >> 6;
  bf16x8 af[2][2], bf01[2][2], bf23[2][2];

  STGA3(0, 0); STGB3(0, 0, 0); STGB3(0, 1, 0);
  STGB3(1, 0, 1); STGB3(1, 1, 1);
  asm volatile("s_waitcnt vmcnt(4)" ::: "memory");
  __builtin_amdgcn_s_barrier();

  for (int it = 0; it < (NKT >> 1); ++it) {
    const int t1  = 2 * it + 1;
    const int t0n = (2 * it + 2 < NKT) ? 2 * it + 2 : NKT - 1;
    const int t1n = (t1 + 2 < NKT) ? t1 + 2 : NKT - 1;

    LDA3(0, 0); LDB3(0, 0, bf01); STGA3(1, t1);
    BAR1(); MM3(0, 0, bf01); BAR2();
    LDB3(0, 1, bf23);
    BAR1(); MM3(0, 1, bf23); BAR2();
    LDA3(0, 1); STGB3(0, 0, t0n);
    BAR1(); MM3(1, 0, bf01); BAR2();
    STGB3(0, 1, t0n);
    BAR1(); MM3(1, 1, bf23); BAR2V4();
    LDA3(1, 0); LDB3(1, 0, bf01); STGA3(0, t0n);
    BAR1(); MM3(0, 0, bf01); BAR2();
    LDB3(1, 1, bf23);
    BAR1(); MM3(0, 1, bf23); BAR2();
    LDA3(1, 1); STGB3(1, 0, t1n);
    BAR1(); MM3(1, 0, bf01); BAR2();
    STGB3(1, 1, t1n);
    BAR1(); MM3(1, 1, bf23); BAR2V4();
  }
  asm volatile("s_waitcnt vmcnt(0)" ::: "memory");

#pragma unroll
  for (int i = 0; i < 4; ++i)
#pragma unroll
    for (int j = 0; j < 4; ++j)
#pragma unroll
      for (int r = 0; r < 4; ++r) {
        const int row = m0 + wm * 64 + i * 16 + lg * 4 + r;
        const int col = n0 + wn * 64 + j * 16 + lr;
        Outp[(size_t)row * N + col] = acc[i][j][r];
      }
}

// ---------------------------------------------------------------------------
// Flash attention v8 + T5 setprio (best config); QK stride 4096, V from vT.
// ---------------------------------------------------------------------------
__global__ __launch_bounds__(256, 2)
void attn_fwd(const unsigned short* __restrict__ qk, const unsigned short* __restrict__ vT,
              unsigned short* __restrict__ outp)
{
  constexpr int T = 2048, ROWS = 4096;
  const int blk = blockIdx.x;
  const int qt = 31 - (blk >> 5);       // heavy tiles first (greedy LPT)
  const int bh = blk & 31;
  const int b = bh >> 4, h = bh & 15;
  const int q0 = qt * 64;
  const int tid = threadIdx.x;
  const int wid = tid >> 6, lane = tid & 63;
  const int lg = lane >> 4, lr = lane & 15;

  __shared__ __align__(16) char Ks[128 * 256];  // 32KB [128 k][128 d] swizzled
  __shared__ __align__(16) char Vt[128 * 256];  // 32KB [128 d][128 k] swizzled
  __shared__ __align__(16) char Ps[64 * 256];   // 16KB [64 q][128 k] swizzled

  const int srow = wid * 4 + (lane >> 4);
  const int scol = (((lane & 15) ^ (srow & 7)) << 3);

  const size_t qrow = (size_t)(b * T + q0 + wid * 16 + lr) * ROWS + h * 128;
  bf16x8 qf[4];
#pragma unroll
  for (int kd = 0; kd < 4; ++kd)
    qf[kd] = __builtin_bit_cast(bf16x8, *(const u16x8*)(qk + qrow + kd * 32 + lg * 8));

  const f32x4 z4 = {0.f, 0.f, 0.f, 0.f};
  f32x4 oacc[8];
#pragma unroll
  for (int jj = 0; jj < 8; ++jj) oacc[jj] = z4;
  float mrow[4] = {-1e30f, -1e30f, -1e30f, -1e30f};
  float lsum[4] = {0.f, 0.f, 0.f, 0.f};
  const float scale2 = 0.12751745f;   // (1/sqrt(128)) * log2(e)

  const int nt = (qt >> 1) + 1;
  for (int kt = 0; kt < nt; ++kt) {
    __syncthreads();
#pragma unroll
    for (int c = 0; c < 8; ++c) {
      gload16(qk + (size_t)(b * T + kt * 128 + c * 16 + srow) * ROWS + 2048 + h * 128 + scol,
              Ks + c * 4096 + wid * 1024);
      gload16(vT + ((size_t)bh * 128 + c * 16 + srow) * 2048 + kt * 128 + scol,
              Vt + c * 4096 + wid * 1024);
    }
    asm volatile("s_waitcnt vmcnt(0)" ::: "memory");
    __syncthreads();

    f32x4 sf[8];
#pragma unroll
    for (int j = 0; j < 8; ++j) sf[j] = z4;
    __builtin_amdgcn_s_setprio(1);
#pragma unroll
    for (int kd = 0; kd < 4; ++kd) {
      const int cb = (kd * 32 + lg * 8) * 2;
#pragma unroll
      for (int j = 0; j < 8; ++j) {
        const int row = j * 16 + lr;
        bf16x8 kf = *(const bf16x8*)(Ks + row * 256 + (cb ^ ((row & 7) << 4)));
        sf[j] = __builtin_amdgcn_mfma_f32_16x16x32_bf16(qf[kd], kf, sf[j], 0, 0, 0);
      }
    }
    __builtin_amdgcn_s_setprio(0);

    const bool diag = (kt == nt - 1);
#pragma unroll
    for (int j = 0; j < 8; ++j)
#pragma unroll
      for (int r = 0; r < 4; ++r) {
        float s = sf[j][r] * scale2;
        const int key = kt * 128 + j * 16 + lr;
        const int qi  = q0 + wid * 16 + lg * 4 + r;
        if (diag && key > qi) s = -1e30f;
        sf[j][r] = s;
      }
    float pm[4];
#pragma unroll
    for (int r = 0; r < 4; ++r) {
      float m0 = fmaxf(fmaxf(sf[0][r], sf[1][r]), fmaxf(sf[2][r], sf[3][r]));
      float m1 = fmaxf(fmaxf(sf[4][r], sf[5][r]), fmaxf(sf[6][r], sf[7][r]));
      pm[r] = red16max(fmaxf(m0, m1));
    }
    const float growth = fmaxf(fmaxf(pm[0] - mrow[0], pm[1] - mrow[1]),
                               fmaxf(pm[2] - mrow[2], pm[3] - mrow[3]));
    const bool resc = !__all(growth <= 11.5f);
    float alpha[4];
    if (resc) {
#pragma unroll
      for (int r = 0; r < 4; ++r) {
        const float mn = fmaxf(mrow[r], pm[r]);
        alpha[r] = exp2f(mrow[r] - mn);
        mrow[r] = mn;
      }
    }
    float rs[4] = {0.f, 0.f, 0.f, 0.f};
#pragma unroll
    for (int j = 0; j < 8; ++j)
#pragma unroll
      for (int r = 0; r < 4; ++r) {
        const float p = exp2f(sf[j][r] - mrow[r]);
        sf[j][r] = p;
        rs[r] += p;
      }
    if (resc) {
#pragma unroll
      for (int r = 0; r < 4; ++r) lsum[r] = lsum[r] * alpha[r] + red16sum(rs[r]);
    } else {
#pragma unroll
      for (int r = 0; r < 4; ++r) lsum[r] += red16sum(rs[r]);
    }

#pragma unroll
    for (int j = 0; j < 8; ++j)
#pragma unroll
      for (int r = 0; r < 4; ++r) {
        const int prow = wid * 16 + lg * 4 + r;
        const int pcol = j * 16 + lr;
        *(unsigned short*)(Ps + prow * 256 + ((pcol * 2) ^ ((prow & 7) << 4))) = f2bf(sf[j][r]);
      }
    if (resc) {
#pragma unroll
      for (int jj = 0; jj < 8; ++jj)
#pragma unroll
        for (int r = 0; r < 4; ++r) oacc[jj][r] *= alpha[r];
    }
    asm volatile("s_waitcnt lgkmcnt(0)" ::: "memory");
    __builtin_amdgcn_sched_barrier(0);

    __builtin_amdgcn_s_setprio(1);
#pragma unroll
    for (int kk = 0; kk < 4; ++kk) {
      const int prow = wid * 16 + lr;
      const int pcb = (kk * 32 + lg * 8) * 2;
      bf16x8 pf = *(const bf16x8*)(Ps + prow * 256 + (pcb ^ ((prow & 7) << 4)));
#pragma unroll
      for (int jj = 0; jj < 8; ++jj) {
        const int vrow = jj * 16 + lr;
        bf16x8 vf = *(const bf16x8*)(Vt + vrow * 256 + (pcb ^ ((vrow & 7) << 4)));
        oacc[jj] = __builtin_amdgcn_mfma_f32_16x16x32_bf16(pf, vf, oacc[jj], 0, 0, 0);
      }
    }
    __builtin_amdgcn_s_setprio(0);
  }

  // epilogue
#pragma unroll
  for (int jj = 0; jj < 8; ++jj)
#pragma unroll
    for (int r = 0; r < 4; ++r) {
      const int q = q0 + wid * 16 + lg * 4 + r;
      const int col = h * 128 + jj * 16 + lr;
      const float o = oacc[jj][r] / lsum[r];
      outp[(size_t)(b * T + q) * 2048 + col] = f2bf(o);
    }
}

// ---------------------------------------------------------------------------
extern "C" void kernel_launch(void* const* d_in, const int* in_sizes, int n_in,
                              void* d_out, int out_size, void* d_ws, size_t ws_size,
                              hipStream_t stream) {
  (void)in_sizes; (void)n_in; (void)out_size; (void)ws_size;
  const float* x     = (const float*)d_in[0];   // [2,2048,2048]
  const float* qkvw  = (const float*)d_in[1];   // [6144,2048]
  const float* projw = (const float*)d_in[2];   // [2048,2048]

  // qkv intermediate (25.2M elems) reshaped: QK row-major [4096][4096] + V^T
  unsigned short* qkb    = (unsigned short*)d_ws;               // [4096][4096]
  unsigned short* vT     = qkb + (size_t)4096 * 4096;           // [32*128][2048]
  unsigned short* attnb  = qkb + (size_t)4096 * 6144;           // [4096][2048]
  unsigned short* xb     = attnb  + (size_t)4096 * 2048;        // [4096][2048]
  unsigned short* qkvwb  = xb     + (size_t)4096 * 2048;        // [6144][2048]
  unsigned short* projwb = qkvwb  + (size_t)6144 * 2048;        // [2048][2048]
  float* out = (float*)d_out;                                   // [4096][2048] f32

  static bool attr_set = false;
  if (!attr_set) {
    hipFuncSetAttribute((const void*)gemm_n192,
                        hipFuncAttributeMaxDynamicSharedMemorySize, 114688);
    hipFuncSetAttribute((const void*)gemm128x256,
                        hipFuncAttributeMaxDynamicSharedMemorySize, 98304);
    attr_set = true;
  }

  cvt3_f32_bf16<<<4096 + 6144 + 2048, 256, 0, stream>>>(
      x, xb, 4096, qkvw, qkvwb, 6144, projw, projwb);
  gemm_n192<<<dim3(6144 / 192, 4096 / 256), 512, 114688, stream>>>(
      xb, qkvwb, qkb, vT, 4096, 6144, 2048);
  attn_fwd<<<1024, 256, 0, stream>>>(qkb, vT, attnb);
  gemm128x256<<<dim3(2048 / 256, 4096 / 128), 512, 98304, stream>>>(
      attnb, projwb, out, 4096, 2048, 2048);
}